// Round 5
// baseline (183.291 us; speedup 1.0000x reference)
//
#include <hip/hip_runtime.h>
#include <hip/hip_fp16.h>

#define CNUM 29
#define HH 256
#define WW 256
#define BB 2
#define KK 7
#define HALO 3
#define TX 32
#define TY 8
#define LW (TX + 2*HALO)   // 38
#define LH (TY + 2*HALO)   // 14
#define NPIX (LH*LW)       // 532
#define HWP (HH*WW)        // 65536

// 1-D normalized Gaussian, sigma=3.0, K=7 (exp(-d^2/18)/sum) — constexpr so
// GW[i]*GW[j] folds to a literal per unrolled tap.
__device__ constexpr float GW[KK] = {
    0.106287146f, 0.140321912f, 0.165770643f, 0.175240699f,
    0.165770643f, 0.140321912f, 0.106287146f};

__device__ __forceinline__ unsigned packh2(float a, float b) {
    __half2 h = __floats2half2_rn(a, b);
    return *reinterpret_cast<unsigned*>(&h);
}
__device__ __forceinline__ float2 unpkh2(unsigned u) {
    __half2 h = *reinterpret_cast<__half2*>(&u);
    return __half22float2(h);
}

// One CRF iteration, 512 threads per 32x8 tile: threads split in two halves by
// channel (h0: ch0-15, h1: ch16-28). q lives in global as fp16 channel-last
// [pix][4 x uint4]; LDS copy is chunk-XOR-swizzled. Softmax joined via a
// 2-scalar LDS exchange. FIRST: q0=softmax(-unary) computed in staging, and
// img is repacked to float4 in ws for later iters. LAST: planar f32 to d_out.
template <bool FIRST, bool LAST>
__global__ __launch_bounds__(512) void crf_iter(const float* __restrict__ unary,
                                                const float* __restrict__ img,
                                                const uint4* __restrict__ qin,
                                                uint4* __restrict__ qout,
                                                float4* __restrict__ img4,
                                                float* __restrict__ outf) {
    __shared__ uint4  s_q4[NPIX * 4];     // 34,048 B (32 fp16 ch/pixel)
    __shared__ float4 s_im[NPIX];         //  8,512 B (r,g,b,0)
    __shared__ float  s_red[2][2][256];   //  4,096 B (max/sum exchange)

    const int tid = threadIdx.x;
    const int hf  = tid >> 8;          // channel half (wave-uniform)
    const int lid = tid & 255;
    const int tx = lid & (TX - 1);
    const int ty = lid >> 5;
    const int bx = blockIdx.x * TX;
    const int by = blockIdx.y * TY;
    const int b  = blockIdx.z;

    const float* ubase = unary + (size_t)b * CNUM * HWP;

    // ---- staging ----
    if (FIRST) {
        const float* imgb = img + (size_t)b * 3 * HWP;
        for (int t = tid; t < NPIX; t += 512) {
            int r = t / LW, cc = t - r * LW;
            int gy = by + r - HALO, gx = bx + cc - HALO;
            bool ok = (gy >= 0) & (gy < HH) & (gx >= 0) & (gx < WW);
            int goff = ok ? gy * WW + gx : 0;
            float4 p;
            p.x = imgb[goff]; p.y = imgb[HWP + goff]; p.z = imgb[2 * HWP + goff];
            p.w = 0.f;
            if (!ok) { p.x = 0.f; p.y = 0.f; p.z = 0.f; }
            s_im[t] = p;
            bool interior = (r >= HALO) & (r < LH - HALO) & (cc >= HALO) & (cc < LW - HALO);
            if (interior) img4[(size_t)b * HWP + goff] = p;  // each pixel written by its owner block

            float v[32];
            float mm = -1e30f;
#pragma unroll
            for (int c = 0; c < CNUM; ++c) {
                v[c] = -ubase[(size_t)c * HWP + goff];
                mm = fmaxf(mm, v[c]);
            }
            float ss = 0.f;
#pragma unroll
            for (int c = 0; c < CNUM; ++c) { v[c] = __expf(v[c] - mm); ss += v[c]; }
            float inv = ok ? 1.f / ss : 0.f;
#pragma unroll
            for (int c = 0; c < CNUM; ++c) v[c] *= inv;
#pragma unroll
            for (int c = CNUM; c < 32; ++c) v[c] = 0.f;
            const int swz = (t >> 1) & 3;
#pragma unroll
            for (int g = 0; g < 4; ++g) {
                uint4 pk;
                pk.x = packh2(v[8 * g + 0], v[8 * g + 1]);
                pk.y = packh2(v[8 * g + 2], v[8 * g + 3]);
                pk.z = packh2(v[8 * g + 4], v[8 * g + 5]);
                pk.w = packh2(v[8 * g + 6], v[8 * g + 7]);
                s_q4[t * 4 + (g ^ swz)] = pk;
            }
        }
    } else {
        for (int t = tid; t < NPIX; t += 512) {
            int r = t / LW, cc = t - r * LW;
            int gy = by + r - HALO, gx = bx + cc - HALO;
            bool ok = (gy >= 0) & (gy < HH) & (gx >= 0) & (gx < WW);
            int goff = ok ? gy * WW + gx : 0;
            float4 p = img4[(size_t)b * HWP + goff];
            if (!ok) { p.x = 0.f; p.y = 0.f; p.z = 0.f; }
            s_im[t] = p;
        }
        const uint4* qb = qin + (size_t)b * HWP * 4;
        for (int u = tid; u < NPIX * 4; u += 512) {
            int t = u >> 2, g = u & 3;
            int r = t / LW, cc = t - r * LW;
            int gy = by + r - HALO, gx = bx + cc - HALO;
            bool ok = (gy >= 0) & (gy < HH) & (gx >= 0) & (gx < WW);
            int goff = ok ? gy * WW + gx : 0;
            uint4 vv = qb[goff * 4 + g];
            if (!ok) { vv.x = 0u; vv.y = 0u; vv.z = 0u; vv.w = 0u; }
            s_q4[t * 4 + (g ^ ((t >> 1) & 3))] = vv;
        }
    }
    __syncthreads();

    // ---- 49-tap message passing: this half's 16 channels ----
    const int tc = (ty + HALO) * LW + (tx + HALO);
    const float4 cp = s_im[tc];
    const int g0 = 2 * hf, g1 = 2 * hf + 1;

    float acc[16];
#pragma unroll
    for (int k = 0; k < 16; ++k) acc[k] = 0.f;

#pragma unroll
    for (int i = 0; i < KK; ++i) {
#pragma unroll
        for (int j = 0; j < KK; ++j) {
            const int t = (ty + i) * LW + (tx + j);
            float4 ip = s_im[t];
            float d0 = ip.x - cp.x, d1 = ip.y - cp.y, d2 = ip.z - cp.z;
            float dsq = d0 * d0 + d1 * d1 + d2 * d2;
            float w = (GW[i] * GW[j]) * (3.0f + 10.0f * __expf(dsq * -0.005f));
            const int t4 = t * 4;
            const int swz = (t >> 1) & 3;
            uint4 qa = s_q4[t4 + (g0 ^ swz)];
            uint4 qc = s_q4[t4 + (g1 ^ swz)];
            const unsigned* ua = &qa.x;
            const unsigned* uc = &qc.x;
#pragma unroll
            for (int k = 0; k < 4; ++k) {
                float2 f = unpkh2(ua[k]);
                acc[2 * k]     += w * f.x;
                acc[2 * k + 1] += w * f.y;
            }
#pragma unroll
            for (int k = 0; k < 4; ++k) {
                float2 f = unpkh2(uc[k]);
                acc[8 + 2 * k]     += w * f.x;
                acc[8 + 2 * k + 1] += w * f.y;
            }
        }
    }

    // ---- joined channel softmax (2-scalar exchange) + store ----
    const int pix = (by + ty) * WW + (bx + tx);
    const float* up = ubase + pix;
    float l[16];
    float m_loc = -1e30f;
    if (hf == 0) {
#pragma unroll
        for (int k = 0; k < 16; ++k) {
            l[k] = acc[k] - up[(size_t)k * HWP];
            m_loc = fmaxf(m_loc, l[k]);
        }
    } else {
#pragma unroll
        for (int k = 0; k < 13; ++k) {
            l[k] = acc[k] - up[(size_t)(16 + k) * HWP];
            m_loc = fmaxf(m_loc, l[k]);
        }
        l[13] = -1e30f; l[14] = -1e30f; l[15] = -1e30f;  // pad -> exp = 0
    }
    s_red[0][hf][lid] = m_loc;
    __syncthreads();
    const float m = fmaxf(s_red[0][0][lid], s_red[0][1][lid]);
    float s_loc = 0.f;
#pragma unroll
    for (int k = 0; k < 16; ++k) { l[k] = __expf(l[k] - m); s_loc += l[k]; }
    s_red[1][hf][lid] = s_loc;
    __syncthreads();
    const float inv = 1.0f / (s_red[1][0][lid] + s_red[1][1][lid]);

    if (LAST) {
        float* qo = outf + (size_t)b * CNUM * HWP + pix;
        if (hf == 0) {
#pragma unroll
            for (int k = 0; k < 16; ++k) qo[(size_t)k * HWP] = l[k] * inv;
        } else {
#pragma unroll
            for (int k = 0; k < 13; ++k) qo[(size_t)(16 + k) * HWP] = l[k] * inv;
        }
    } else {
        uint4* qo = qout + ((size_t)b * HWP + pix) * 4;
        uint4 p0, p1;
        p0.x = packh2(l[0] * inv,  l[1] * inv);
        p0.y = packh2(l[2] * inv,  l[3] * inv);
        p0.z = packh2(l[4] * inv,  l[5] * inv);
        p0.w = packh2(l[6] * inv,  l[7] * inv);
        p1.x = packh2(l[8] * inv,  l[9] * inv);
        p1.y = packh2(l[10] * inv, l[11] * inv);
        p1.z = packh2(l[12] * inv, l[13] * inv);
        p1.w = packh2(l[14] * inv, l[15] * inv);   // hf1 pads are exactly 0
        qo[2 * hf]     = p0;
        qo[2 * hf + 1] = p1;
    }
}

extern "C" void kernel_launch(void* const* d_in, const int* in_sizes, int n_in,
                              void* d_out, int out_size, void* d_ws, size_t ws_size,
                              hipStream_t stream) {
    const float* unary = (const float*)d_in[0];
    const float* img   = (const float*)d_in[1];
    // ws layout: qA fp16 (8.39 MB) | qB fp16 (8.39 MB) | img4 (2.10 MB)
    uint4*  qA   = (uint4*)d_ws;
    uint4*  qB   = (uint4*)((char*)d_ws + (size_t)BB * HWP * 64);
    float4* img4 = (float4*)((char*)d_ws + (size_t)2 * BB * HWP * 64);
    float*  outf = (float*)d_out;

    dim3 grid(WW / TX, HH / TY, BB);
    crf_iter<true,  false><<<grid, 512, 0, stream>>>(unary, img, qA, qA, img4, outf); // i1: unary -> qA (+img4)
    crf_iter<false, false><<<grid, 512, 0, stream>>>(unary, img, qA, qB, img4, outf); // i2
    crf_iter<false, false><<<grid, 512, 0, stream>>>(unary, img, qB, qA, img4, outf); // i3
    crf_iter<false, false><<<grid, 512, 0, stream>>>(unary, img, qA, qB, img4, outf); // i4
    crf_iter<false, true ><<<grid, 512, 0, stream>>>(unary, img, qB, qA, img4, outf); // i5 -> d_out
}